// Round 6
// baseline (38.425 us; speedup 1.0000x reference)
//
#include <hip/hip_runtime.h>
#include <hip/hip_bf16.h>

// RGCN layer (R=8, B=4, N=1024, I=O=64, NB=4) on MI355X.
//
// Slot folding: out[o] = relu(bias[o] + sum_{j=9o..9o+8} concat[j]).
// Channel c of relation r -> o=(64r+c)/9, slot s=(r+c)/9 in [0,8).
// Folded weights w~[i][s]; slot read-back s = o - 7r.
//
//  prep_kernel : 288 blocks; w~ fold; x~[rb][n][8] f32 via MFMA; self blocks
//                -> selfP[b][n][8].
//  agg_kernel  : 256 blocks x 256 thr (1/CU). Block=(rb, 128-row m-chunk):
//                reads a CONTIGUOUS 512 KB adj stripe, one full 4 KB row per
//                iteration (256 thr x int4). Depth-16 named-reg prefetch.
//                Thread owns 4 n-columns -> no cross-thread acc reduce, no
//                atomics. deg row-sums byte-packed in LDS, tail-reduced,
//                non-atomic write (block owns its (rb,m) range).
//                Partials -> aggP[chunk][rb][n][8] (deterministic).
//  out_kernel  : out[o] = relu(bias + sum_c term(r1) + [r2!=r1] sum_c term(r2)),
//                term(r) = (sum of 8 chunk partials)/(deg+eps); r==8 -> selfP.

#define NN 1024
#define EPSK 1e-7f

typedef __bf16 bf16x8 __attribute__((ext_vector_type(8)));
typedef float f32x4 __attribute__((ext_vector_type(4)));

__device__ __forceinline__ unsigned short f2bf(float f) {
  union { float f; unsigned int u; } v; v.f = f;
  return (unsigned short)((v.u + 0x7FFFu + ((v.u >> 16) & 1u)) >> 16);
}

// ---------------------------------------------------------------------------
// prep: 288 blocks x 256 thr. bid<256: (r,b,chunk) -> x~ f32. bid>=256: self.
// ---------------------------------------------------------------------------
__global__ __launch_bounds__(256) void prep_kernel(
    const float* __restrict__ feat,    // [4,1024,64]
    const float* __restrict__ weight,  // [4,64,64]
    const float* __restrict__ Wo,      // [64,64]
    const float* __restrict__ wcmp,    // [8,4]
    float* __restrict__ xf,            // [32][1024][8] f32
    float* __restrict__ selfP)         // [4][1024][8] f32
{
  __shared__ __align__(16) unsigned short featL[128 * 72];  // [n][i] bf16
  __shared__ __align__(16) float wTf[64 * 65];              // [c][i] f32
  __shared__ __align__(16) unsigned short wfold[16 * 72];   // [s][i] bf16
  __shared__ __align__(16) float stg[128 * 8];              // [n][s] f32 bounce

  const int bid = blockIdx.x;
  const int t = threadIdx.x;
  const bool isSelf = bid >= 256;
  int r, b, chunk;
  if (!isSelf) { r = bid >> 5; b = (bid >> 3) & 3; chunk = bid & 7; }
  else { const int s2 = bid - 256; b = s2 >> 3; chunk = s2 & 7; r = 8; }
  const int n0 = chunk << 7;

  // stage features chunk [128 n][64 i] -> bf16 LDS
  const float* fsrc = feat + ((size_t)(b * NN + n0)) * 64;
  #pragma unroll
  for (int p = 0; p < 8; ++p) {
    const int idx = p * 256 + t;
    const int row = idx >> 4, c4 = idx & 15;
    const float4 v = *reinterpret_cast<const float4*>(fsrc + row * 64 + c4 * 4);
    ushort4 u;
    u.x = f2bf(v.x); u.y = f2bf(v.y); u.z = f2bf(v.z); u.w = f2bf(v.w);
    *reinterpret_cast<ushort4*>(&featL[row * 72 + c4 * 4]) = u;
  }

  // wTf[c][i] = w_full[i][c] (relation) or Wo[i][c] (self)
  if (!isSelf) {
    const float wc0 = wcmp[r * 4 + 0], wc1 = wcmp[r * 4 + 1];
    const float wc2 = wcmp[r * 4 + 2], wc3 = wcmp[r * 4 + 3];
    #pragma unroll
    for (int jj = 0; jj < 16; ++jj) {
      const int e = jj * 256 + t;
      const int i = e >> 6, c = e & 63;
      wTf[c * 65 + i] = wc0 * weight[i * 64 + c] + wc1 * weight[4096 + i * 64 + c] +
                        wc2 * weight[8192 + i * 64 + c] + wc3 * weight[12288 + i * 64 + c];
    }
  } else {
    #pragma unroll
    for (int jj = 0; jj < 16; ++jj) {
      const int e = jj * 256 + t;
      const int i = e >> 6, c = e & 63;
      wTf[c * 65 + i] = Wo[i * 64 + c];
    }
  }
  __syncthreads();

  // fold: wfold[s][i] = sum_{c : (r+c)/9 == s} wTf[c][i]; rows 8..15 zero
  #pragma unroll
  for (int jj = 0; jj < 4; ++jj) {
    const int e = jj * 256 + t;
    const int s = e >> 6, i = e & 63;
    float sum = 0.f;
    if (s < 8) {
      const int c0 = 9 * s - r;
      const int clo = c0 < 0 ? 0 : c0;
      const int chi = (c0 + 8 > 63) ? 63 : c0 + 8;
      for (int c = clo; c <= chi; ++c) sum += wTf[c * 65 + i];
    }
    wfold[s * 72 + i] = f2bf(sum);
  }
  __syncthreads();

  const int w = t >> 6, lane = t & 63;
  const int li = lane & 15, lg = lane >> 4;

  // MFMA: D[slot][n] = sum_i wfold[slot][i] * featL[n][i]
  f32x4 acc0 = {0.f, 0.f, 0.f, 0.f}, acc1 = {0.f, 0.f, 0.f, 0.f};
  #pragma unroll
  for (int ks = 0; ks < 2; ++ks) {
    const int kof = ks * 32 + lg * 8;
    const bf16x8 af = __builtin_bit_cast(bf16x8,
        *reinterpret_cast<const uint4*>(&wfold[li * 72 + kof]));
    const bf16x8 b0 = __builtin_bit_cast(bf16x8,
        *reinterpret_cast<const uint4*>(&featL[((2 * w + 0) * 16 + li) * 72 + kof]));
    const bf16x8 b1 = __builtin_bit_cast(bf16x8,
        *reinterpret_cast<const uint4*>(&featL[((2 * w + 1) * 16 + li) * 72 + kof]));
    acc0 = __builtin_amdgcn_mfma_f32_16x16x32_bf16(af, b0, acc0, 0, 0, 0);
    acc1 = __builtin_amdgcn_mfma_f32_16x16x32_bf16(af, b1, acc1, 0, 0, 0);
  }

  // lane holds D[slot=lg*4+qq][n=tile*16+li]; slots >=8 are zero -> drop
  if (lg < 2) {
    #pragma unroll
    for (int qq = 0; qq < 4; ++qq) {
      const int s = lg * 4 + qq;
      stg[((2 * w + 0) * 16 + li) * 8 + s] = acc0[qq];
      stg[((2 * w + 1) * 16 + li) * 8 + s] = acc1[qq];
    }
  }
  __syncthreads();
  // coalesced copy out: 4 KB = 256 thr x 16 B
  {
    float* dstF = isSelf ? (selfP + ((size_t)(b * NN + n0)) * 8)
                         : (xf + ((size_t)((r * 4 + b) * NN + n0)) * 8);
    *reinterpret_cast<float4*>(dstF + t * 4) =
        *reinterpret_cast<const float4*>(&stg[t * 4]);
  }
}

// ---------------------------------------------------------------------------
// agg: 256 blocks x 256 thr (1/CU). Block=(rb, mchunk of 128 contiguous rows).
// ---------------------------------------------------------------------------
#define BODY(PK, G, K, PF)                                                      \
  {                                                                             \
    const int4 cur_ = PK;                                                       \
    if (PF) {                                                                   \
      PK = *reinterpret_cast<const int4*>(asrc + ((((G) << 4) + (K) + 16) << 10)); \
    }                                                                           \
    const int ps_ = cur_.x + cur_.y + cur_.z + cur_.w;                          \
    pk |= ((unsigned int)ps_) << (8 * ((K) & 3));                               \
    const float a0_ = (float)cur_.x, a1_ = (float)cur_.y;                       \
    const float a2_ = (float)cur_.z, a3_ = (float)cur_.w;                       \
    const float4 xlo_ =                                                         \
        *reinterpret_cast<const float4*>(&xsL[(((G) << 4) + (K)) * 8]);         \
    const float4 xhi_ =                                                         \
        *reinterpret_cast<const float4*>(&xsL[(((G) << 4) + (K)) * 8 + 4]);     \
    const float xv_[8] = {xlo_.x, xlo_.y, xlo_.z, xlo_.w,                       \
                          xhi_.x, xhi_.y, xhi_.z, xhi_.w};                      \
    _Pragma("unroll")                                                           \
    for (int s_ = 0; s_ < 8; ++s_) {                                            \
      acc0[s_] = fmaf(a0_, xv_[s_], acc0[s_]);                                  \
      acc1[s_] = fmaf(a1_, xv_[s_], acc1[s_]);                                  \
      acc2[s_] = fmaf(a2_, xv_[s_], acc2[s_]);                                  \
      acc3[s_] = fmaf(a3_, xv_[s_], acc3[s_]);                                  \
    }                                                                           \
    if (((K) & 3) == 3) {                                                       \
      degL[((G) * 4 + ((K) >> 2)) * 260 + t] = pk;                              \
      pk = 0u;                                                                  \
    }                                                                           \
  }

#define GROUP(G, PF)                                                            \
  BODY(P0, G, 0, PF) BODY(P1, G, 1, PF) BODY(P2, G, 2, PF) BODY(P3, G, 3, PF)   \
  BODY(P4, G, 4, PF) BODY(P5, G, 5, PF) BODY(P6, G, 6, PF) BODY(P7, G, 7, PF)   \
  BODY(P8, G, 8, PF) BODY(P9, G, 9, PF) BODY(P10, G, 10, PF)                    \
  BODY(P11, G, 11, PF) BODY(P12, G, 12, PF) BODY(P13, G, 13, PF)                \
  BODY(P14, G, 14, PF) BODY(P15, G, 15, PF)

__global__ __launch_bounds__(256, 1) void agg_kernel(
    const int* __restrict__ adj,    // [32][1024][1024]
    const float* __restrict__ xf,   // [32][1024][8] f32
    float* __restrict__ aggP,       // [8 chunk][32 rb][1024 n][8 s] f32
    float* __restrict__ deg)        // [32][1024] f32
{
  __shared__ __align__(16) float xsL[128 * 8];            // x~ rows, 4 KB
  __shared__ __align__(16) unsigned int degL[32 * 260];   // packed deg, 33 KB

  const int bid = blockIdx.x;
  const int rb = bid >> 3, mc = bid & 7;
  const int m0 = mc << 7;
  const int t = threadIdx.x;

  const int* asrc = adj + (((size_t)rb) << 20) + (((size_t)m0) << 10) + (t << 2);

  // depth-16 prefetch: rows 0..15 of this chunk (one full 4 KB row per load set)
  int4 P0  = *reinterpret_cast<const int4*>(asrc + (0 << 10));
  int4 P1  = *reinterpret_cast<const int4*>(asrc + (1 << 10));
  int4 P2  = *reinterpret_cast<const int4*>(asrc + (2 << 10));
  int4 P3  = *reinterpret_cast<const int4*>(asrc + (3 << 10));
  int4 P4  = *reinterpret_cast<const int4*>(asrc + (4 << 10));
  int4 P5  = *reinterpret_cast<const int4*>(asrc + (5 << 10));
  int4 P6  = *reinterpret_cast<const int4*>(asrc + (6 << 10));
  int4 P7  = *reinterpret_cast<const int4*>(asrc + (7 << 10));
  int4 P8  = *reinterpret_cast<const int4*>(asrc + (8 << 10));
  int4 P9  = *reinterpret_cast<const int4*>(asrc + (9 << 10));
  int4 P10 = *reinterpret_cast<const int4*>(asrc + (10 << 10));
  int4 P11 = *reinterpret_cast<const int4*>(asrc + (11 << 10));
  int4 P12 = *reinterpret_cast<const int4*>(asrc + (12 << 10));
  int4 P13 = *reinterpret_cast<const int4*>(asrc + (13 << 10));
  int4 P14 = *reinterpret_cast<const int4*>(asrc + (14 << 10));
  int4 P15 = *reinterpret_cast<const int4*>(asrc + (15 << 10));

  // stage x~ rows [m0, m0+128): 4 KB
  {
    const float* xs = xf + ((size_t)(rb * NN + m0)) * 8;
    *reinterpret_cast<float4*>(&xsL[t * 4]) =
        *reinterpret_cast<const float4*>(xs + t * 4);
  }

  float acc0[8], acc1[8], acc2[8], acc3[8];
  #pragma unroll
  for (int s = 0; s < 8; ++s) { acc0[s] = 0.f; acc1[s] = 0.f; acc2[s] = 0.f; acc3[s] = 0.f; }

  __syncthreads();  // xsL ready (also drains initial prefetch once — negligible)

  unsigned int pk = 0u;
  for (int g = 0; g < 7; ++g) {
    GROUP(g, 1)
  }
  GROUP(7, 0)

  // acc writeout: thread owns n = 4t..4t+3, 32 consecutive floats
  {
    float* dst = aggP + (((size_t)(mc * 32 + rb)) * NN + 4 * (size_t)t) * 8;
    *reinterpret_cast<float4*>(dst + 0)  = make_float4(acc0[0], acc0[1], acc0[2], acc0[3]);
    *reinterpret_cast<float4*>(dst + 4)  = make_float4(acc0[4], acc0[5], acc0[6], acc0[7]);
    *reinterpret_cast<float4*>(dst + 8)  = make_float4(acc1[0], acc1[1], acc1[2], acc1[3]);
    *reinterpret_cast<float4*>(dst + 12) = make_float4(acc1[4], acc1[5], acc1[6], acc1[7]);
    *reinterpret_cast<float4*>(dst + 16) = make_float4(acc2[0], acc2[1], acc2[2], acc2[3]);
    *reinterpret_cast<float4*>(dst + 20) = make_float4(acc2[4], acc2[5], acc2[6], acc2[7]);
    *reinterpret_cast<float4*>(dst + 24) = make_float4(acc3[0], acc3[1], acc3[2], acc3[3]);
    *reinterpret_cast<float4*>(dst + 28) = make_float4(acc3[4], acc3[5], acc3[6], acc3[7]);
  }

  __syncthreads();  // degL complete

  // deg tail reduce: thread t<128 owns row m0+t; sum 256 byte-partials
  if (t < 128) {
    const unsigned int* src = &degL[(t >> 2) * 260];
    const int sh = 8 * (t & 3);
    int sum = 0;
    #pragma unroll
    for (int c4 = 0; c4 < 64; ++c4) {
      const uint4 v = *reinterpret_cast<const uint4*>(src + c4 * 4);
      sum += (int)((v.x >> sh) & 0xFFu) + (int)((v.y >> sh) & 0xFFu) +
             (int)((v.z >> sh) & 0xFFu) + (int)((v.w >> sh) & 0xFFu);
    }
    deg[rb * NN + m0 + t] = (float)sum;  // exclusive owner — non-atomic
  }
}

// ---------------------------------------------------------------------------
// epilogue: combine 8 chunk-partials + self, divide by deg, bias, relu
// ---------------------------------------------------------------------------
__global__ __launch_bounds__(256) void out_kernel(
    const float* __restrict__ aggP,   // [8][32][1024][8]
    const float* __restrict__ selfP,  // [4][1024][8]
    const float* __restrict__ deg,    // [32][1024]
    const float* __restrict__ bias, float* __restrict__ out)
{
  const int gid = blockIdx.x * 256 + threadIdx.x;
  const int o = gid & 63;
  const int n = (gid >> 6) & 1023;
  const int b = gid >> 16;

  const int r1 = (9 * o) >> 6;
  const int r2 = (9 * o + 8) >> 6;

  float acc = bias[o];
  #pragma unroll
  for (int pass = 0; pass < 2; ++pass) {
    const int r = pass ? r2 : r1;
    if (pass && r2 == r1) break;
    float v;
    if (r < 8) {
      const int s = o - 7 * r;
      const size_t base = (((size_t)(r * 4 + b)) * NN + n) * 8 + s;
      float sum = 0.f;
      #pragma unroll
      for (int c = 0; c < 8; ++c) sum += aggP[base + (size_t)c * 262144];
      v = sum / (deg[(r * 4 + b) * NN + n] + EPSK);
    } else {
      v = selfP[((size_t)(b * NN + n)) * 8 + (o - 56)];
    }
    acc += v;
  }
  out[gid] = fmaxf(acc, 0.0f);
}

extern "C" void kernel_launch(void* const* d_in, const int* in_sizes, int n_in,
                              void* d_out, int out_size, void* d_ws, size_t ws_size,
                              hipStream_t stream) {
  const float* feat   = (const float*)d_in[0];
  const int*   adj    = (const int*)d_in[1];
  const float* weight = (const float*)d_in[2];
  const float* Wo     = (const float*)d_in[3];
  const float* wcmp   = (const float*)d_in[4];
  const float* bias   = (const float*)d_in[5];
  float* out = (float*)d_out;

  // ws: x~ f32 (1 MiB) | selfP (128 KiB) | aggP (8 MiB) | deg (128 KiB)
  char* ws = (char*)d_ws;
  float* xf    = (float*)(ws);
  float* selfP = (float*)(ws + 1048576u);
  float* aggP  = (float*)(ws + 1048576u + 131072u);
  float* deg   = (float*)(ws + 1048576u + 131072u + 8388608u);

  prep_kernel<<<dim3(288), dim3(256), 0, stream>>>(feat, weight, Wo, wcmp, xf, selfP);
  agg_kernel<<<dim3(256), dim3(256), 0, stream>>>(adj, xf, aggP, deg);
  out_kernel<<<dim3(1024), dim3(256), 0, stream>>>(aggP, selfP, deg, bias, out);
}